// Round 8
// baseline (2066.424 us; speedup 1.0000x reference)
//
#include <hip/hip_runtime.h>
#include <hip/hip_bf16.h>

#define HLAT 181
#define WLON 360
#define HW (HLAT * WLON)
#define HPAD 188
#define WPAD 368
#define PCH ((size_t)HPAD * WPAD * 16)   // ushorts per chunk-plane

typedef __attribute__((ext_vector_type(8)))  short short8v;
typedef __attribute__((ext_vector_type(16))) float f32x16;

static __device__ __forceinline__ ushort bf16_hi_bits(float f) {
  union { float f; unsigned u; } c; c.f = f;
  unsigned u = c.u;
  unsigned rounded = u + 0x7FFF + ((u >> 16) & 1);  // RNE
  return (ushort)(rounded >> 16);
}
static __device__ __forceinline__ float bf16_to_f(ushort b) {
  union { unsigned u; float f; } c; c.u = ((unsigned)b) << 16;
  return c.f;
}

// ---------------- kernel 0: weight prep ----------------
// w2f entry idx = (tap*8+ch)*4 + m*2 + p ; each entry = 64 short8 (lane l)
//   lane l, j: part p of w2[oc=m*32+(l&31)][ci=ch*16+(l>>5)*8+j][tap]
// w1t[o][28]: padded copy of w1 (col 27 = 0). w3t[c*25+ij][4].
__global__ __launch_bounds__(256) void k_tw(const float* __restrict__ w2,
                                            const float* __restrict__ w3,
                                            const float* __restrict__ w1,
                                            ushort* __restrict__ w2f,
                                            float* __restrict__ w3t,
                                            float* __restrict__ w1t) {
  int idx = blockIdx.x * 256 + threadIdx.x;
  if (idx < 51200) {
    int l   = idx & 63;
    int p   = (idx >> 6) & 1;
    int m   = (idx >> 7) & 1;
    int ch  = (idx >> 8) & 7;
    int tap = idx >> 11;
    int oc  = m * 32 + (l & 31);
    int ci0 = ch * 16 + (l >> 5) * 8;
#pragma unroll
    for (int j = 0; j < 8; ++j) {
      float f = w2[(oc * 128 + ci0 + j) * 25 + tap];
      ushort hi = bf16_hi_bits(f);
      ushort v;
      if (p == 0) v = hi;
      else        v = bf16_hi_bits(f - bf16_to_f(hi));
      w2f[(size_t)idx * 8 + j] = v;
    }
  }
  if (idx < 1600 * 4) {
    int ck = idx >> 2, o = idx & 3;
    int c = ck / 25, ij = ck % 25;
    w3t[idx] = (o < 3) ? w3[(o * 64 + c) * 25 + ij] : 0.f;
  }
  if (idx < 3584) {
    int o = idx / 28, q = idx % 28;
    w1t[idx] = (q < 27) ? w1[o * 27 + q] : 0.f;
  }
}

// ---------------- zero ONLY the pad ring pixels (4024 per plane) ----------
__global__ __launch_bounds__(256) void k_zring(ushort* __restrict__ h1s) {
  const int i = blockIdx.x * 256 + threadIdx.x;
  if (i >= 4024) return;
  int row, col;
  if (i < 736)       { row = i / 368;              col = i % 368; }
  else if (i < 2576) { int p = i - 736;  row = 183 + p / 368; col = p % 368; }
  else if (i < 2938) { int p = i - 2576; row = 2 + p % 181;   col = p / 181; }
  else               { int p = i - 2938; row = 2 + p % 181;   col = 362 + p / 181; }
  short8v z = {0, 0, 0, 0, 0, 0, 0, 0};
  short8v* d = (short8v*)(h1s + (size_t)blockIdx.y * PCH + ((size_t)row * 368 + col) * 16);
  d[0] = z; d[1] = z;
}

// ---------------- kernel 1: disco conv + w1 GEMM + relu (LDS-free) -------
// h1s plane index: (bi*2+part)*8 + ch ; layout [yi][xi][16ci] (bf16 bits)
__global__ __launch_bounds__(192) void k_l1(const float* __restrict__ x,
    const float* __restrict__ psi, const float* __restrict__ quad,
    const float* __restrict__ w1t, const float* __restrict__ b1,
    ushort* __restrict__ h1s, int b0) {
  const int h = blockIdx.x;
  const int bi = blockIdx.y;
  const int b = b0 + bi;
  const int tid = threadIdx.x;
  if (tid >= 180) return;

  float z[2][28];
#pragma unroll
  for (int q = 0; q < 28; ++q) { z[0][q] = 0.f; z[1][q] = 0.f; }

#pragma unroll 1
  for (int i = 0; i < 5; ++i) {
    int hi = h + i - 2;
    hi = hi < 0 ? 0 : (hi >= HLAT ? HLAT - 1 : hi);
    const float qv = quad[hi];                 // uniform -> scalar load
    float pv[45];                              // uniform psi slice for this i
#pragma unroll
    for (int kk = 0; kk < 9; ++kk)
#pragma unroll
      for (int j = 0; j < 5; ++j)
        pv[kk * 5 + j] = psi[((size_t)(kk * HLAT + h)) * 25 + i * 5 + j];
#pragma unroll
    for (int c = 0; c < 3; ++c) {
      const float* row = x + ((size_t)(b * 3 + c) * HLAT + hi) * WLON;
      float v0[5], v1[5];
#pragma unroll
      for (int j = 0; j < 5; ++j) {
        int wj0 = tid + j - 2; wj0 = wj0 < 0 ? wj0 + WLON : wj0;
        int wj1 = tid + 180 + j - 2; wj1 = wj1 >= WLON ? wj1 - WLON : wj1;
        v0[j] = row[wj0] * qv;
        v1[j] = row[wj1] * qv;
      }
#pragma unroll
      for (int kk = 0; kk < 9; ++kk) {
        float a0 = 0.f, a1 = 0.f;
#pragma unroll
        for (int j = 0; j < 5; ++j) {
          const float p = pv[kk * 5 + j];
          a0 += p * v0[j];
          a1 += p * v1[j];
        }
        z[0][c * 9 + kk] += a0;
        z[1][c * 9 + kk] += a1;
      }
    }
  }
  z[0][27] = 0.f; z[1][27] = 0.f;

  ushort* base = h1s + (size_t)bi * 16 * PCH;
  const size_t poff0 = ((size_t)(h + 2) * WPAD + (tid + 2)) * 16;
  const size_t poff1 = ((size_t)(h + 2) * WPAD + (tid + 180 + 2)) * 16;

  for (int chv = 0; chv < 8; ++chv) {
    union { ushort u[16]; short8v v[2]; } h0b, l0b, h1b, l1b;
#pragma unroll
    for (int oo = 0; oo < 16; ++oo) {
      const int o = chv * 16 + oo;
      float a0 = b1[o], a1 = a0;               // uniform -> scalar load
#pragma unroll
      for (int q4 = 0; q4 < 7; ++q4) {
        const float4 wv = *(const float4*)&w1t[o * 28 + q4 * 4];  // uniform
        a0 += wv.x * z[0][q4 * 4 + 0] + wv.y * z[0][q4 * 4 + 1] +
              wv.z * z[0][q4 * 4 + 2] + wv.w * z[0][q4 * 4 + 3];
        a1 += wv.x * z[1][q4 * 4 + 0] + wv.y * z[1][q4 * 4 + 1] +
              wv.z * z[1][q4 * 4 + 2] + wv.w * z[1][q4 * 4 + 3];
      }
      a0 = fmaxf(a0, 0.f); a1 = fmaxf(a1, 0.f);
      const ushort hb0 = bf16_hi_bits(a0);
      const ushort hb1 = bf16_hi_bits(a1);
      h0b.u[oo] = hb0; l0b.u[oo] = bf16_hi_bits(a0 - bf16_to_f(hb0));
      h1b.u[oo] = hb1; l1b.u[oo] = bf16_hi_bits(a1 - bf16_to_f(hb1));
    }
    ushort* phi = base + (size_t)chv * PCH;            // part 0
    ushort* plo = base + (size_t)(8 + chv) * PCH;      // part 1
    *(short8v*)(phi + poff0) = h0b.v[0]; *(short8v*)(phi + poff0 + 8) = h0b.v[1];
    *(short8v*)(plo + poff0) = l0b.v[0]; *(short8v*)(plo + poff0 + 8) = l0b.v[1];
    *(short8v*)(phi + poff1) = h1b.v[0]; *(short8v*)(phi + poff1 + 8) = h1b.v[1];
    *(short8v*)(plo + poff1) = l1b.v[0]; *(short8v*)(plo + poff1 + 8) = l1b.v[1];
  }
}

// ---------------- kernel 2: conv 128->64 via bf16x3 MFMA ------------------
// grid (6, 23, bc) block 256 (4 waves as 2x2). Tile: 64oc x 8rows x 64cols.
// 16 passes of (ch, part): only ONE activation part staged per pass ->
// 27.6 KB/buffer, dbuf 55.3 KB -> 2 blocks/CU (2 waves/SIMD) for latency
// hiding. hi pass: AhBh+AlBh (4 MFMA per r,di); lo pass: AhBl (2 MFMA).
__global__ __launch_bounds__(256, 2) void k_conv2(const ushort* __restrict__ h1s,
    const ushort* __restrict__ w2f, const float* __restrict__ b2,
    float* __restrict__ h2) {
  __shared__ ushort act[2][12][72][16];  // [buf][row][col][ci16] = 55296 B
  const int x0 = blockIdx.x * 64;
  const int y0 = blockIdx.y * 8;
  const int bi = blockIdx.z;
  const int tid = threadIdx.x;
  const int wv = tid >> 6;
  const int wr = wv >> 1;         // row-group 0..1
  const int wc = wv & 1;          // col-group 0..1
  const int l = tid & 63;
  const int l31 = l & 31;
  const int q8 = (l >> 5) * 8;

  f32x16 acc[4][2];
#pragma unroll
  for (int r = 0; r < 4; ++r)
#pragma unroll
    for (int m = 0; m < 2; ++m)
#pragma unroll
      for (int e = 0; e < 16; ++e) acc[r][m][e] = 0.f;

  const short8v* wf = (const short8v*)w2f;
  const ushort* pbase = h1s + (size_t)bi * 16 * PCH;

  auto stage = [&](int buf, int pass) {
    const int part = pass & 1, ch = pass >> 1;
    const ushort* pl = pbase + (size_t)(part * 8 + ch) * PCH;
#pragma unroll
    for (int s = 0; s < 9; ++s) {
      const int k = wv * 9 + s;           // 0..35
      const int t = k / 3;                // row 0..11
      const int slot = k % 3;
      if (slot < 2) {
        const int c0 = slot * 32;
        const ushort* g = pl + ((size_t)(y0 + t) * WPAD + (x0 + c0 + (l >> 1))) * 16 + (l & 1) * 8;
        __builtin_amdgcn_global_load_lds(
            (const __attribute__((address_space(1))) unsigned int*)g,
            (__attribute__((address_space(3))) unsigned int*)&act[buf][t][c0][0], 16, 0, 0);
      } else {
        const ushort* g = pl + ((size_t)(y0 + t) * WPAD + (x0 + 64 + (l >> 3))) * 16 + (l & 7) * 2;
        __builtin_amdgcn_global_load_lds(
            (const __attribute__((address_space(1))) unsigned int*)g,
            (__attribute__((address_space(3))) unsigned int*)&act[buf][t][64][0], 4, 0, 0);
      }
    }
  };

  // prologue: stage pass 0 (ch 0, hi)
  stage(0, 0);
  asm volatile("s_waitcnt vmcnt(0)" ::: "memory");
  __syncthreads();

#pragma unroll 1
  for (int p = 0; p < 16; ++p) {
    const int cur = p & 1;
    if (p < 15) stage(cur ^ 1, p + 1);   // prefetch next pass
    const int ch = p >> 1;
    if ((p & 1) == 0) {
      // ---- hi pass: acc[r][m] += A_m_hi*Bh + A_m_lo*Bh ----
#pragma unroll 1
      for (int dj = 0; dj < 5; ++dj) {
        short8v aw[5][4];
#pragma unroll
        for (int di = 0; di < 5; ++di) {
          const size_t e0 = (size_t)(((di * 5 + dj) * 8 + ch) * 4) * 64 + l;
          aw[di][0] = wf[e0];
          aw[di][1] = wf[e0 + 64];
          aw[di][2] = wf[e0 + 128];
          aw[di][3] = wf[e0 + 192];
        }
        __builtin_amdgcn_s_setprio(1);
#pragma unroll
        for (int rr = 0; rr < 8; ++rr) {
          const int t = wr * 4 + rr;
          const int c = wc * 32 + l31 + dj;      // <= 67 < 72, in-bounds
          const short8v bv = *(const short8v*)&act[cur][t][c][q8];
#pragma unroll
          for (int di = 0; di < 5; ++di) {
            const int r = rr - di;
            if (r < 0 || r > 3) continue;        // compile-time after unroll
            acc[r][0] = __builtin_amdgcn_mfma_f32_32x32x16_bf16(aw[di][0], bv, acc[r][0], 0, 0, 0);
            acc[r][0] = __builtin_amdgcn_mfma_f32_32x32x16_bf16(aw[di][1], bv, acc[r][0], 0, 0, 0);
            acc[r][1] = __builtin_amdgcn_mfma_f32_32x32x16_bf16(aw[di][2], bv, acc[r][1], 0, 0, 0);
            acc[r][1] = __builtin_amdgcn_mfma_f32_32x32x16_bf16(aw[di][3], bv, acc[r][1], 0, 0, 0);
          }
        }
        __builtin_amdgcn_s_setprio(0);
      }
    } else {
      // ---- lo pass: acc[r][m] += A_m_hi*Bl ----
#pragma unroll 1
      for (int dj = 0; dj < 5; ++dj) {
        short8v aw2[5][2];
#pragma unroll
        for (int di = 0; di < 5; ++di) {
          const size_t e0 = (size_t)(((di * 5 + dj) * 8 + ch) * 4) * 64 + l;
          aw2[di][0] = wf[e0];
          aw2[di][1] = wf[e0 + 128];
        }
        __builtin_amdgcn_s_setprio(1);
#pragma unroll
        for (int rr = 0; rr < 8; ++rr) {
          const int t = wr * 4 + rr;
          const int c = wc * 32 + l31 + dj;
          const short8v bv = *(const short8v*)&act[cur][t][c][q8];
#pragma unroll
          for (int di = 0; di < 5; ++di) {
            const int r = rr - di;
            if (r < 0 || r > 3) continue;
            acc[r][0] = __builtin_amdgcn_mfma_f32_32x32x16_bf16(aw2[di][0], bv, acc[r][0], 0, 0, 0);
            acc[r][1] = __builtin_amdgcn_mfma_f32_32x32x16_bf16(aw2[di][1], bv, acc[r][1], 0, 0, 0);
          }
        }
        __builtin_amdgcn_s_setprio(0);
      }
    }
    asm volatile("s_waitcnt vmcnt(0)" ::: "memory");
    __syncthreads();
  }

  // ---- epilogue: bias + relu + store ----
  const int xg = x0 + wc * 32 + l31;
  if (xg < WLON) {
#pragma unroll
    for (int r = 0; r < 4; ++r) {
      const int y = y0 + wr * 4 + r;
      if (y >= HLAT) continue;
#pragma unroll
      for (int m = 0; m < 2; ++m) {
#pragma unroll
        for (int e = 0; e < 16; ++e) {
          const int oc = m * 32 + (e & 3) + 8 * (e >> 2) + (q8 >> 1);
          h2[((size_t)(bi * 64 + oc) * HLAT + y) * WLON + xg] =
              fmaxf(acc[r][m][e] + b2[oc], 0.f);
        }
      }
    }
  }
}

// ---------------- kernel 3: conv 64->3, 5x5, zero pad (f32) ---------------
// w3 read directly from global with uniform index -> s_load (no LDS storm).
__global__ __launch_bounds__(256) void k_conv3(const float* __restrict__ h2,
    const float* __restrict__ w3t, const float* __restrict__ b3,
    float* __restrict__ out, int b0) {
  const int x0 = blockIdx.x * 128;
  const int y0 = blockIdx.y * 8;
  const int bi = blockIdx.z;
  __shared__ __align__(16) float s_in[4][12][136];
  const int tid = threadIdx.x;
  const int ry = tid >> 5;
  const int cx0 = (tid & 31) << 2;

  float acc[3][4];
#pragma unroll
  for (int o = 0; o < 3; ++o)
#pragma unroll
    for (int p = 0; p < 4; ++p) acc[o][p] = 0.f;

  for (int cc = 0; cc < 16; ++cc) {
    __syncthreads();
    for (int idx = tid; idx < 4 * 12 * 132; idx += 256) {
      const int ci = idx / (12 * 132);
      const int r = (idx / 132) % 12;
      const int col = idx % 132;
      const int yy = y0 + r - 2;
      const int xx = x0 + col - 2;
      float v = 0.f;
      if (yy >= 0 && yy < HLAT && xx >= 0 && xx < WLON)
        v = h2[((size_t)(bi * 64 + cc * 4 + ci) * HLAT + yy) * WLON + xx];
      s_in[ci][r][col] = v;
    }
    __syncthreads();
#pragma unroll
    for (int ci = 0; ci < 4; ++ci) {
#pragma unroll
      for (int i = 0; i < 5; ++i) {
        const float4 a4 = *(const float4*)&s_in[ci][ry + i][cx0];
        const float4 b4 = *(const float4*)&s_in[ci][ry + i][cx0 + 4];
        const float win[8] = {a4.x, a4.y, a4.z, a4.w, b4.x, b4.y, b4.z, b4.w};
#pragma unroll
        for (int j = 0; j < 5; ++j) {
          const float4 w4 = *(const float4*)&w3t[(((cc * 4 + ci) * 25) + i * 5 + j) * 4];
          const float wv3[3] = {w4.x, w4.y, w4.z};
#pragma unroll
          for (int p = 0; p < 4; ++p) {
            const float v = win[j + p];
#pragma unroll
            for (int o = 0; o < 3; ++o) acc[o][p] += wv3[o] * v;
          }
        }
      }
    }
  }
  const int oy = y0 + ry;
  const int b = b0 + bi;
  if (oy < HLAT) {
#pragma unroll
    for (int o = 0; o < 3; ++o) {
      const float bb = b3[o];
      float* dst = out + ((size_t)(b * 3 + o) * HLAT + oy) * WLON;
#pragma unroll
      for (int p = 0; p < 4; ++p) {
        const int ox = x0 + cx0 + p;
        if (ox < WLON) dst[ox] = acc[o][p] + bb;
      }
    }
  }
}

extern "C" void kernel_launch(void* const* d_in, const int* in_sizes, int n_in,
                              void* d_out, int out_size, void* d_ws, size_t ws_size,
                              hipStream_t stream) {
  const float* x    = (const float*)d_in[0];
  const float* psi  = (const float*)d_in[1];
  const float* quad = (const float*)d_in[2];
  const float* w1   = (const float*)d_in[3];
  const float* b1   = (const float*)d_in[4];
  const float* w2   = (const float*)d_in[5];
  const float* b2   = (const float*)d_in[6];
  const float* w3   = (const float*)d_in[7];
  const float* b3   = (const float*)d_in[8];
  float* out = (float*)d_out;
  float* ws  = (float*)d_ws;

  float*  w3t = ws;                       // 6400 floats
  ushort* w2f = (ushort*)(ws + 6400);     // 409600 ushorts (= 204800 floats)
  float*  w1t = ws + 211200;              // 3584 floats
  const size_t HEAD = 214784;             // floats

  size_t wsf = ws_size / 4;
  const size_t h1s_f = PCH * 8;           // floats per batch for 16 chunk-planes
  const size_t per_b = h1s_f + (size_t)64 * HW;
  int bc = 8;
  while (bc > 1 && HEAD + (size_t)bc * per_b > wsf) bc >>= 1;

  ushort* h1s = (ushort*)(ws + HEAD);
  float*  h2  = ws + HEAD + (size_t)bc * h1s_f;

  k_tw<<<dim3(200), dim3(256), 0, stream>>>(w2, w3, w1, w2f, w3t, w1t);
  k_zring<<<dim3(16, bc * 16), dim3(256), 0, stream>>>(h1s);

  for (int b0 = 0; b0 < 8; b0 += bc) {
    int cur = 8 - b0 < bc ? 8 - b0 : bc;
    k_l1<<<dim3(HLAT, cur), dim3(192), 0, stream>>>(x, psi, quad, w1t, b1, h1s, b0);
    k_conv2<<<dim3(6, 23, cur), dim3(256), 0, stream>>>(h1s, w2f, b2, h2);
    k_conv3<<<dim3(3, 23, cur), dim3(256), 0, stream>>>(h2, w3t, b3, out, b0);
  }
}

// Round 9
// 1121.136 us; speedup vs baseline: 1.8432x; 1.8432x over previous
//
#include <hip/hip_runtime.h>
#include <hip/hip_bf16.h>

#define HLAT 181
#define WLON 360
#define HW (HLAT * WLON)
#define HPAD 188
#define WPAD 368
#define PCH ((size_t)HPAD * WPAD * 16)   // ushorts per chunk-plane

typedef __attribute__((ext_vector_type(8)))  short short8v;
typedef __attribute__((ext_vector_type(16))) float f32x16;

static __device__ __forceinline__ ushort bf16_hi_bits(float f) {
  union { float f; unsigned u; } c; c.f = f;
  unsigned u = c.u;
  unsigned rounded = u + 0x7FFF + ((u >> 16) & 1);  // RNE
  return (ushort)(rounded >> 16);
}
static __device__ __forceinline__ float bf16_to_f(ushort b) {
  union { unsigned u; float f; } c; c.u = ((unsigned)b) << 16;
  return c.f;
}

// ---------------- kernel 0: weight prep ----------------
// w2f entry idx = (tap*8+ch)*4 + m*2 + p ; each entry = 64 short8 (lane l)
//   lane l, j: part p of w2[oc=m*32+(l&31)][ci=ch*16+(l>>5)*8+j][tap]
// w1t[o][28]: padded copy of w1 (col 27 = 0). w3t[c*25+ij][4].
__global__ __launch_bounds__(256) void k_tw(const float* __restrict__ w2,
                                            const float* __restrict__ w3,
                                            const float* __restrict__ w1,
                                            ushort* __restrict__ w2f,
                                            float* __restrict__ w3t,
                                            float* __restrict__ w1t) {
  int idx = blockIdx.x * 256 + threadIdx.x;
  if (idx < 51200) {
    int l   = idx & 63;
    int p   = (idx >> 6) & 1;
    int m   = (idx >> 7) & 1;
    int ch  = (idx >> 8) & 7;
    int tap = idx >> 11;
    int oc  = m * 32 + (l & 31);
    int ci0 = ch * 16 + (l >> 5) * 8;
#pragma unroll
    for (int j = 0; j < 8; ++j) {
      float f = w2[(oc * 128 + ci0 + j) * 25 + tap];
      ushort hi = bf16_hi_bits(f);
      ushort v;
      if (p == 0) v = hi;
      else        v = bf16_hi_bits(f - bf16_to_f(hi));
      w2f[(size_t)idx * 8 + j] = v;
    }
  }
  if (idx < 1600 * 4) {
    int ck = idx >> 2, o = idx & 3;
    int c = ck / 25, ij = ck % 25;
    w3t[idx] = (o < 3) ? w3[(o * 64 + c) * 25 + ij] : 0.f;
  }
  if (idx < 3584) {
    int o = idx / 28, q = idx % 28;
    w1t[idx] = (q < 27) ? w1[o * 27 + q] : 0.f;
  }
}

// ---------------- zero ONLY the pad ring pixels (4024 per plane) ----------
__global__ __launch_bounds__(256) void k_zring(ushort* __restrict__ h1s) {
  const int i = blockIdx.x * 256 + threadIdx.x;
  if (i >= 4024) return;
  int row, col;
  if (i < 736)       { row = i / 368;              col = i % 368; }
  else if (i < 2576) { int p = i - 736;  row = 183 + p / 368; col = p % 368; }
  else if (i < 2938) { int p = i - 2576; row = 2 + p % 181;   col = p / 181; }
  else               { int p = i - 2938; row = 2 + p % 181;   col = 362 + p / 181; }
  short8v z = {0, 0, 0, 0, 0, 0, 0, 0};
  short8v* d = (short8v*)(h1s + (size_t)blockIdx.y * PCH + ((size_t)row * 368 + col) * 16);
  d[0] = z; d[1] = z;
}

// ---------------- kernel 1: disco conv + w1 GEMM + relu (LDS-free) -------
// h1s plane index: (bi*2+part)*8 + ch ; layout [yi][xi][16ci] (bf16 bits)
__global__ __launch_bounds__(192) void k_l1(const float* __restrict__ x,
    const float* __restrict__ psi, const float* __restrict__ quad,
    const float* __restrict__ w1t, const float* __restrict__ b1,
    ushort* __restrict__ h1s, int b0) {
  const int h = blockIdx.x;
  const int bi = blockIdx.y;
  const int b = b0 + bi;
  const int tid = threadIdx.x;
  if (tid >= 180) return;

  float z[2][28];
#pragma unroll
  for (int q = 0; q < 28; ++q) { z[0][q] = 0.f; z[1][q] = 0.f; }

#pragma unroll 1
  for (int i = 0; i < 5; ++i) {
    int hi = h + i - 2;
    hi = hi < 0 ? 0 : (hi >= HLAT ? HLAT - 1 : hi);
    const float qv = quad[hi];                 // uniform -> scalar load
    float pv[45];                              // uniform psi slice for this i
#pragma unroll
    for (int kk = 0; kk < 9; ++kk)
#pragma unroll
      for (int j = 0; j < 5; ++j)
        pv[kk * 5 + j] = psi[((size_t)(kk * HLAT + h)) * 25 + i * 5 + j];
#pragma unroll
    for (int c = 0; c < 3; ++c) {
      const float* row = x + ((size_t)(b * 3 + c) * HLAT + hi) * WLON;
      float v0[5], v1[5];
#pragma unroll
      for (int j = 0; j < 5; ++j) {
        int wj0 = tid + j - 2; wj0 = wj0 < 0 ? wj0 + WLON : wj0;
        int wj1 = tid + 180 + j - 2; wj1 = wj1 >= WLON ? wj1 - WLON : wj1;
        v0[j] = row[wj0] * qv;
        v1[j] = row[wj1] * qv;
      }
#pragma unroll
      for (int kk = 0; kk < 9; ++kk) {
        float a0 = 0.f, a1 = 0.f;
#pragma unroll
        for (int j = 0; j < 5; ++j) {
          const float p = pv[kk * 5 + j];
          a0 += p * v0[j];
          a1 += p * v1[j];
        }
        z[0][c * 9 + kk] += a0;
        z[1][c * 9 + kk] += a1;
      }
    }
  }
  z[0][27] = 0.f; z[1][27] = 0.f;

  ushort* base = h1s + (size_t)bi * 16 * PCH;
  const size_t poff0 = ((size_t)(h + 2) * WPAD + (tid + 2)) * 16;
  const size_t poff1 = ((size_t)(h + 2) * WPAD + (tid + 180 + 2)) * 16;

  for (int chv = 0; chv < 8; ++chv) {
    union { ushort u[16]; short8v v[2]; } h0b, l0b, h1b, l1b;
#pragma unroll
    for (int oo = 0; oo < 16; ++oo) {
      const int o = chv * 16 + oo;
      float a0 = b1[o], a1 = a0;               // uniform -> scalar load
#pragma unroll
      for (int q4 = 0; q4 < 7; ++q4) {
        const float4 wv = *(const float4*)&w1t[o * 28 + q4 * 4];  // uniform
        a0 += wv.x * z[0][q4 * 4 + 0] + wv.y * z[0][q4 * 4 + 1] +
              wv.z * z[0][q4 * 4 + 2] + wv.w * z[0][q4 * 4 + 3];
        a1 += wv.x * z[1][q4 * 4 + 0] + wv.y * z[1][q4 * 4 + 1] +
              wv.z * z[1][q4 * 4 + 2] + wv.w * z[1][q4 * 4 + 3];
      }
      a0 = fmaxf(a0, 0.f); a1 = fmaxf(a1, 0.f);
      const ushort hb0 = bf16_hi_bits(a0);
      const ushort hb1 = bf16_hi_bits(a1);
      h0b.u[oo] = hb0; l0b.u[oo] = bf16_hi_bits(a0 - bf16_to_f(hb0));
      h1b.u[oo] = hb1; l1b.u[oo] = bf16_hi_bits(a1 - bf16_to_f(hb1));
    }
    ushort* phi = base + (size_t)chv * PCH;            // part 0
    ushort* plo = base + (size_t)(8 + chv) * PCH;      // part 1
    *(short8v*)(phi + poff0) = h0b.v[0]; *(short8v*)(phi + poff0 + 8) = h0b.v[1];
    *(short8v*)(plo + poff0) = l0b.v[0]; *(short8v*)(plo + poff0 + 8) = l0b.v[1];
    *(short8v*)(phi + poff1) = h1b.v[0]; *(short8v*)(phi + poff1 + 8) = h1b.v[1];
    *(short8v*)(plo + poff1) = l1b.v[0]; *(short8v*)(plo + poff1 + 8) = l1b.v[1];
  }
}

// ---------------- kernel 2: conv 128->64 via bf16x3 MFMA ------------------
// grid (12, 23, bc) block 256 (4 waves = m-half x row-group).
// Tile: 64oc x 8rows x 32cols; wave = 32oc x 4rows x 32cols.
// acc = 64 regs/wave, aw = 40 VGPR -> fits 128/128 split, NO spill.
// Dbuf LDS 61.4 KB -> 2 blocks/CU = 2 waves/SIMD for latency hiding.
__global__ __launch_bounds__(256, 2) void k_conv2(const ushort* __restrict__ h1s,
    const ushort* __restrict__ w2f, const float* __restrict__ b2,
    float* __restrict__ h2) {
  __shared__ ushort act[2][2][12][40][16];  // [buf][part][row][col][ci16] = 61440 B
  const int x0 = blockIdx.x * 32;
  const int y0 = blockIdx.y * 8;
  const int bi = blockIdx.z;
  const int tid = threadIdx.x;
  const int wv = tid >> 6;
  const int m  = wv >> 1;         // oc half (0..1)
  const int wr = wv & 1;          // row-group (0..1)
  const int l = tid & 63;
  const int l31 = l & 31;
  const int q8 = (l >> 5) * 8;

  f32x16 acc[4];
#pragma unroll
  for (int r = 0; r < 4; ++r)
#pragma unroll
    for (int e = 0; e < 16; ++e) acc[r][e] = 0.f;

  const short8v* wf = (const short8v*)w2f;
  const ushort* pbase = h1s + (size_t)bi * 16 * PCH;

  auto stage = [&](int buf, int ch) {
#pragma unroll
    for (int s = 0; s < 12; ++s) {
      const int k = wv * 12 + s;          // 0..47
      const int part = k / 24;
      const int rem = k - part * 24;
      const int t = rem >> 1;             // row 0..11
      const int slot = rem & 1;
      const ushort* pl = pbase + (size_t)(part * 8 + ch) * PCH;
      if (slot == 0) {
        // cols 0..31: lane l -> col l>>1, ci-half l&1 (16B granules)
        const ushort* g = pl + ((size_t)(y0 + t) * WPAD + (x0 + (l >> 1))) * 16 + (l & 1) * 8;
        __builtin_amdgcn_global_load_lds(
            (const __attribute__((address_space(1))) unsigned int*)g,
            (__attribute__((address_space(3))) unsigned int*)&act[buf][part][t][0][0], 16, 0, 0);
      } else {
        // cols 32..39: lane l -> col 32+(l>>3), ci2 (l&7) (4B granules)
        const ushort* g = pl + ((size_t)(y0 + t) * WPAD + (x0 + 32 + (l >> 3))) * 16 + (l & 7) * 2;
        __builtin_amdgcn_global_load_lds(
            (const __attribute__((address_space(1))) unsigned int*)g,
            (__attribute__((address_space(3))) unsigned int*)&act[buf][part][t][32][0], 4, 0, 0);
      }
    }
  };

  // prologue
  stage(0, 0);
  asm volatile("s_waitcnt vmcnt(0)" ::: "memory");
  __syncthreads();

#pragma unroll 1
  for (int ch = 0; ch < 8; ++ch) {
    const int cur = ch & 1;
    if (ch < 7) stage(cur ^ 1, ch + 1);   // prefetch next chunk (other buffer)
#pragma unroll 1
    for (int dj = 0; dj < 5; ++dj) {
      short8v aw[5][2];                   // [di][hi/lo] for this wave's m
#pragma unroll
      for (int di = 0; di < 5; ++di) {
        const size_t e0 = (size_t)(((di * 5 + dj) * 8 + ch) * 4 + m * 2) * 64 + l;
        aw[di][0] = wf[e0];        // hi part
        aw[di][1] = wf[e0 + 64];   // lo part
      }
      __builtin_amdgcn_s_setprio(1);
#pragma unroll
      for (int rr = 0; rr < 8; ++rr) {
        const int t = wr * 4 + rr;
        const int c = l31 + dj;           // <= 35 < 40, in-bounds
        const short8v bh = *(const short8v*)&act[cur][0][t][c][q8];
        const short8v bl = *(const short8v*)&act[cur][1][t][c][q8];
#pragma unroll
        for (int di = 0; di < 5; ++di) {
          const int r = rr - di;
          if (r < 0 || r > 3) continue;   // compile-time after unroll
          acc[r] = __builtin_amdgcn_mfma_f32_32x32x16_bf16(aw[di][0], bh, acc[r], 0, 0, 0);
          acc[r] = __builtin_amdgcn_mfma_f32_32x32x16_bf16(aw[di][1], bh, acc[r], 0, 0, 0);
          acc[r] = __builtin_amdgcn_mfma_f32_32x32x16_bf16(aw[di][0], bl, acc[r], 0, 0, 0);
        }
      }
      __builtin_amdgcn_s_setprio(0);
    }
    asm volatile("s_waitcnt vmcnt(0)" ::: "memory");
    __syncthreads();
  }

  // ---- epilogue: bias + relu + store ----
  const int xg = x0 + l31;
  if (xg < WLON) {
#pragma unroll
    for (int r = 0; r < 4; ++r) {
      const int y = y0 + wr * 4 + r;
      if (y >= HLAT) continue;
#pragma unroll
      for (int e = 0; e < 16; ++e) {
        const int oc = m * 32 + (e & 3) + 8 * (e >> 2) + (q8 >> 1);
        h2[((size_t)(bi * 64 + oc) * HLAT + y) * WLON + xg] =
            fmaxf(acc[r][e] + b2[oc], 0.f);
      }
    }
  }
}

// ---------------- kernel 3: conv 64->3, 5x5, zero pad (f32, R6 form) ------
__global__ __launch_bounds__(256) void k_conv3(const float* __restrict__ h2,
    const float* __restrict__ w3t, const float* __restrict__ b3,
    float* __restrict__ out, int b0) {
  const int x0 = blockIdx.x * 128;
  const int y0 = blockIdx.y * 8;
  const int bi = blockIdx.z;
  __shared__ __align__(16) float s_w3[1600][4];
  __shared__ __align__(16) float s_in[4][12][136];
  const int tid = threadIdx.x;
  const int ry = tid >> 5;
  const int cx0 = (tid & 31) << 2;

  for (int idx = tid; idx < 1600; idx += 256)
    ((float4*)s_w3)[idx] = ((const float4*)w3t)[idx];

  float acc[3][4];
#pragma unroll
  for (int o = 0; o < 3; ++o)
#pragma unroll
    for (int p = 0; p < 4; ++p) acc[o][p] = 0.f;

  for (int cc = 0; cc < 16; ++cc) {
    __syncthreads();
    for (int idx = tid; idx < 4 * 12 * 132; idx += 256) {
      const int ci = idx / (12 * 132);
      const int r = (idx / 132) % 12;
      const int col = idx % 132;
      const int yy = y0 + r - 2;
      const int xx = x0 + col - 2;
      float v = 0.f;
      if (yy >= 0 && yy < HLAT && xx >= 0 && xx < WLON)
        v = h2[((size_t)(bi * 64 + cc * 4 + ci) * HLAT + yy) * WLON + xx];
      s_in[ci][r][col] = v;
    }
    __syncthreads();
#pragma unroll
    for (int ci = 0; ci < 4; ++ci) {
#pragma unroll
      for (int i = 0; i < 5; ++i) {
        const float4 a4 = *(const float4*)&s_in[ci][ry + i][cx0];
        const float4 b4 = *(const float4*)&s_in[ci][ry + i][cx0 + 4];
        const float win[8] = {a4.x, a4.y, a4.z, a4.w, b4.x, b4.y, b4.z, b4.w};
#pragma unroll
        for (int j = 0; j < 5; ++j) {
          const float4 w4 = *(const float4*)&s_w3[(cc * 4 + ci) * 25 + i * 5 + j][0];
          const float wv3[3] = {w4.x, w4.y, w4.z};
#pragma unroll
          for (int p = 0; p < 4; ++p) {
            const float v = win[j + p];
#pragma unroll
            for (int o = 0; o < 3; ++o) acc[o][p] += wv3[o] * v;
          }
        }
      }
    }
  }
  const int oy = y0 + ry;
  const int b = b0 + bi;
  if (oy < HLAT) {
#pragma unroll
    for (int o = 0; o < 3; ++o) {
      const float bb = b3[o];
      float* dst = out + ((size_t)(b * 3 + o) * HLAT + oy) * WLON;
#pragma unroll
      for (int p = 0; p < 4; ++p) {
        const int ox = x0 + cx0 + p;
        if (ox < WLON) dst[ox] = acc[o][p] + bb;
      }
    }
  }
}

extern "C" void kernel_launch(void* const* d_in, const int* in_sizes, int n_in,
                              void* d_out, int out_size, void* d_ws, size_t ws_size,
                              hipStream_t stream) {
  const float* x    = (const float*)d_in[0];
  const float* psi  = (const float*)d_in[1];
  const float* quad = (const float*)d_in[2];
  const float* w1   = (const float*)d_in[3];
  const float* b1   = (const float*)d_in[4];
  const float* w2   = (const float*)d_in[5];
  const float* b2   = (const float*)d_in[6];
  const float* w3   = (const float*)d_in[7];
  const float* b3   = (const float*)d_in[8];
  float* out = (float*)d_out;
  float* ws  = (float*)d_ws;

  float*  w3t = ws;                       // 6400 floats
  ushort* w2f = (ushort*)(ws + 6400);     // 409600 ushorts (= 204800 floats)
  float*  w1t = ws + 211200;              // 3584 floats
  const size_t HEAD = 214784;             // floats

  size_t wsf = ws_size / 4;
  const size_t h1s_f = PCH * 8;           // floats per batch for 16 chunk-planes
  const size_t per_b = h1s_f + (size_t)64 * HW;
  int bc = 8;
  while (bc > 1 && HEAD + (size_t)bc * per_b > wsf) bc >>= 1;

  ushort* h1s = (ushort*)(ws + HEAD);
  float*  h2  = ws + HEAD + (size_t)bc * h1s_f;

  k_tw<<<dim3(200), dim3(256), 0, stream>>>(w2, w3, w1, w2f, w3t, w1t);
  k_zring<<<dim3(16, bc * 16), dim3(256), 0, stream>>>(h1s);

  for (int b0 = 0; b0 < 8; b0 += bc) {
    int cur = 8 - b0 < bc ? 8 - b0 : bc;
    k_l1<<<dim3(HLAT, cur), dim3(192), 0, stream>>>(x, psi, quad, w1t, b1, h1s, b0);
    k_conv2<<<dim3(12, 23, cur), dim3(256), 0, stream>>>(h1s, w2f, b2, h2);
    k_conv3<<<dim3(3, 23, cur), dim3(256), 0, stream>>>(h2, w3t, b3, out, b0);
  }
}